// Round 1
// baseline (1470.400 us; speedup 1.0000x reference)
//
#include <hip/hip_runtime.h>

#define D 128

// ---------------------------------------------------------------------------
// Kernel 1: edge-parallel scatter-add.  32 lanes per edge, each lane handles
// 4 contiguous floats (float4 load of the source row, 4 atomicAdds into agg).
// ---------------------------------------------------------------------------
__global__ __launch_bounds__(256) void edge_scatter(
    const float* __restrict__ feat, const int* __restrict__ src,
    const int* __restrict__ dst, float* __restrict__ agg, int E) {
  long long t = (long long)blockIdx.x * 256 + threadIdx.x;
  int e = (int)(t >> 5);
  int lane = (int)(t & 31);
  if (e >= E) return;
  int u = src[e];
  int v = dst[e];
  float4 fv = ((const float4*)(feat + (size_t)u * D))[lane];
  float* ap = agg + (size_t)v * D + lane * 4;
  atomicAdd(ap + 0, fv.x);
  atomicAdd(ap + 1, fv.y);
  atomicAdd(ap + 2, fv.z);
  atomicAdd(ap + 3, fv.w);
}

// ---------------------------------------------------------------------------
// Kernel 2: fused  out = feat[:n]*w1^T + b1 + (agg/in_norm)*w2^T + b2
// One thread per output element (o in [0,128)), 2 rows per 256-thread block.
// w1/w2 rows read per-thread with float4 (64 KB each -> L1/L2 resident).
// feat/agg rows are wave-broadcast loads.
// ---------------------------------------------------------------------------
__global__ __launch_bounds__(256) void sage_out(
    const float* __restrict__ feat, const float* __restrict__ in_norm,
    const float* __restrict__ w1, const float* __restrict__ b1,
    const float* __restrict__ w2, const float* __restrict__ b2,
    const float* __restrict__ agg, float* __restrict__ out, int ndst) {
  int o = threadIdx.x & (D - 1);
  int row = blockIdx.x * 2 + (threadIdx.x >> 7);
  if (row >= ndst) return;
  float inv = 1.0f / in_norm[row];
  const float4* fr = (const float4*)(feat + (size_t)row * D);
  const float4* ar = (const float4*)(agg + (size_t)row * D);
  const float4* w1r = (const float4*)(w1 + (size_t)o * D);
  const float4* w2r = (const float4*)(w2 + (size_t)o * D);
  float acc1 = 0.f, acc2 = 0.f;
#pragma unroll 8
  for (int d4 = 0; d4 < D / 4; ++d4) {
    float4 f = fr[d4];
    float4 a = ar[d4];
    float4 x1 = w1r[d4];
    float4 x2 = w2r[d4];
    acc1 += f.x * x1.x + f.y * x1.y + f.z * x1.z + f.w * x1.w;
    acc2 += a.x * x2.x + a.y * x2.y + a.z * x2.z + a.w * x2.w;
  }
  out[(size_t)row * D + o] = acc1 + b1[o] + inv * acc2 + b2[o];
}

extern "C" void kernel_launch(void* const* d_in, const int* in_sizes, int n_in,
                              void* d_out, int out_size, void* d_ws, size_t ws_size,
                              hipStream_t stream) {
  const float* feat    = (const float*)d_in[0];
  const float* in_norm = (const float*)d_in[1];
  const float* w1      = (const float*)d_in[2];
  const float* b1      = (const float*)d_in[3];
  const float* w2      = (const float*)d_in[4];
  const float* b2      = (const float*)d_in[5];
  const int*   src     = (const int*)d_in[6];
  const int*   dst     = (const int*)d_in[7];
  float*       out     = (float*)d_out;

  int E    = in_sizes[6];
  int ndst = in_sizes[1];

  float* agg = (float*)d_ws;  // ndst * 128 floats = 12.8 MB

  // d_ws is poisoned 0xAA and NOT re-poisoned between replays -> zero it
  // ourselves every call (memset node is graph-capturable).
  hipMemsetAsync(agg, 0, (size_t)ndst * D * sizeof(float), stream);

  long long tot = (long long)E * 32;  // 32 lanes per edge
  int blocks = (int)((tot + 255) / 256);
  edge_scatter<<<blocks, 256, 0, stream>>>(feat, src, dst, agg, E);

  int oblocks = (ndst + 1) / 2;  // 2 rows per block
  sage_out<<<oblocks, 256, 0, stream>>>(feat, in_norm, w1, b1, w2, b2, agg, out, ndst);
}

// Round 2
// 230.388 us; speedup vs baseline: 6.3823x; 6.3823x over previous
//
#include <hip/hip_runtime.h>

#define D 128

// ---------------------------------------------------------------------------
// CSR build: histogram -> single-block scan -> scatter src indices
// ---------------------------------------------------------------------------
__global__ __launch_bounds__(256) void hist_kernel(
    const int* __restrict__ dst, int* __restrict__ cnt, int E) {
  int e = blockIdx.x * 256 + threadIdx.x;
  if (e < E) atomicAdd(&cnt[dst[e]], 1);
}

// single block, 1024 threads: exclusive scan of cnt[0..n) -> offs, cursor
__global__ __launch_bounds__(1024) void scan_kernel(
    const int* __restrict__ cnt, int* __restrict__ offs,
    int* __restrict__ cursor, int n) {
  __shared__ int part[1024];
  int t = threadIdx.x;
  int ch = (n + 1023) >> 10;
  int beg = t * ch;
  int end = min(beg + ch, n);
  int s = 0;
  for (int i = beg; i < end; ++i) s += cnt[i];
  part[t] = s;
  __syncthreads();
  // Hillis-Steele inclusive scan (read-both-then-write, double sync)
  for (int off = 1; off < 1024; off <<= 1) {
    int v = part[t];
    int add = (t >= off) ? part[t - off] : 0;
    __syncthreads();
    part[t] = v + add;
    __syncthreads();
  }
  int base = (t == 0) ? 0 : part[t - 1];
  for (int i = beg; i < end; ++i) {
    offs[i] = base;
    cursor[i] = base;
    base += cnt[i];
  }
  if (t == 0) offs[n] = part[1023];
}

__global__ __launch_bounds__(256) void scatter_csr(
    const int* __restrict__ src, const int* __restrict__ dst,
    int* __restrict__ cursor, int* __restrict__ csr, int E) {
  int e = blockIdx.x * 256 + threadIdx.x;
  if (e < E) {
    int p = atomicAdd(&cursor[dst[e]], 1);
    csr[p] = src[e];
  }
}

// ---------------------------------------------------------------------------
// dst-major gather: one wave (64 lanes) per dst row, float2 per lane.
// One coalesced 512B read per edge, one coalesced 512B store per row.
// ---------------------------------------------------------------------------
__global__ __launch_bounds__(256) void gather_rows(
    const float* __restrict__ feat, const int* __restrict__ csr,
    const int* __restrict__ offs, float* __restrict__ agg, int ndst) {
  int row = blockIdx.x * 4 + (threadIdx.x >> 6);
  if (row >= ndst) return;
  int lane = threadIdx.x & 63;
  int beg = offs[row], end = offs[row + 1];
  float2 a0 = make_float2(0.f, 0.f), a1 = make_float2(0.f, 0.f);
  int j = beg;
  for (; j + 1 < end; j += 2) {
    int u0 = csr[j], u1 = csr[j + 1];
    float2 p0 = ((const float2*)(feat + (size_t)u0 * D))[lane];
    float2 p1 = ((const float2*)(feat + (size_t)u1 * D))[lane];
    a0.x += p0.x; a0.y += p0.y;
    a1.x += p1.x; a1.y += p1.y;
  }
  if (j < end) {
    int u = csr[j];
    float2 p = ((const float2*)(feat + (size_t)u * D))[lane];
    a0.x += p.x; a0.y += p.y;
  }
  ((float2*)(agg + (size_t)row * D))[lane] = make_float2(a0.x + a1.x, a0.y + a1.y);
}

// ---------------------------------------------------------------------------
// w transpose: wT[k][o] = w[o][k]  (so GEMM lanes read coalesced over o)
// ---------------------------------------------------------------------------
__global__ __launch_bounds__(256) void transpose_w(
    const float* __restrict__ w1, const float* __restrict__ w2,
    float* __restrict__ w1T, float* __restrict__ w2T) {
  int idx = blockIdx.x * 256 + threadIdx.x;  // 0..16383
  if (idx < D * D) {
    int o = idx & (D - 1);
    int k = idx >> 7;
    w1T[idx] = w1[o * D + k];
    w2T[idx] = w2[o * D + k];
  }
}

// ---------------------------------------------------------------------------
// out = feat[:n]*w1^T + b1 + (agg/in_norm)*w2^T + b2
// 32 rows per block; feat/agg rows staged in LDS (1/in_norm folded in);
// thread (o, mh) accumulates 16 rows; w reads coalesced from w1T/w2T.
// ---------------------------------------------------------------------------
#define MT 32
__global__ __launch_bounds__(256) void out_gemm(
    const float* __restrict__ feat, const float* __restrict__ in_norm,
    const float* __restrict__ agg, const float* __restrict__ w1T,
    const float* __restrict__ w2T, const float* __restrict__ b1,
    const float* __restrict__ b2, float* __restrict__ out, int ndst) {
  __shared__ float sF[MT][D];
  __shared__ float sA[MT][D];
  int tid = threadIdx.x;
  int base = blockIdx.x * MT;
  // stage 32 rows of feat and agg/in_norm: 1024 float4 per array, 4/thread
#pragma unroll
  for (int i = 0; i < 4; ++i) {
    int idx = tid + i * 256;
    int r = idx >> 5;      // 32 float4 per row
    int c4 = idx & 31;
    int gr = base + r;
    float4 f = make_float4(0.f, 0.f, 0.f, 0.f);
    float4 a = f;
    if (gr < ndst) {
      f = ((const float4*)(feat + (size_t)gr * D))[c4];
      float inv = 1.0f / in_norm[gr];
      float4 t = ((const float4*)(agg + (size_t)gr * D))[c4];
      a = make_float4(t.x * inv, t.y * inv, t.z * inv, t.w * inv);
    }
    ((float4*)sF[r])[c4] = f;
    ((float4*)sA[r])[c4] = a;
  }
  __syncthreads();
  int o = tid & (D - 1);
  int mh = tid >> 7;  // 0/1
  float acc[16];
#pragma unroll
  for (int m = 0; m < 16; ++m) acc[m] = 0.f;
  for (int kq = 0; kq < D / 4; ++kq) {
    int k = kq * 4;
    float w1a = w1T[(k + 0) * D + o], w1b = w1T[(k + 1) * D + o];
    float w1c = w1T[(k + 2) * D + o], w1d = w1T[(k + 3) * D + o];
    float w2a = w2T[(k + 0) * D + o], w2b = w2T[(k + 1) * D + o];
    float w2c = w2T[(k + 2) * D + o], w2d = w2T[(k + 3) * D + o];
#pragma unroll
    for (int m = 0; m < 16; ++m) {
      float4 f = ((const float4*)sF[mh * 16 + m])[kq];
      float4 a = ((const float4*)sA[mh * 16 + m])[kq];
      acc[m] += f.x * w1a + f.y * w1b + f.z * w1c + f.w * w1d
              + a.x * w2a + a.y * w2b + a.z * w2c + a.w * w2d;
    }
  }
  float bb = b1[o] + b2[o];
#pragma unroll
  for (int m = 0; m < 16; ++m) {
    int gr = base + mh * 16 + m;
    if (gr < ndst) out[(size_t)gr * D + o] = acc[m] + bb;
  }
}

extern "C" void kernel_launch(void* const* d_in, const int* in_sizes, int n_in,
                              void* d_out, int out_size, void* d_ws, size_t ws_size,
                              hipStream_t stream) {
  const float* feat    = (const float*)d_in[0];
  const float* in_norm = (const float*)d_in[1];
  const float* w1      = (const float*)d_in[2];
  const float* b1      = (const float*)d_in[3];
  const float* w2      = (const float*)d_in[4];
  const float* b2      = (const float*)d_in[5];
  const int*   src     = (const int*)d_in[6];
  const int*   dst     = (const int*)d_in[7];
  float*       out     = (float*)d_out;

  int E    = in_sizes[6];
  int ndst = in_sizes[1];

  // workspace layout (bytes)
  char* ws = (char*)d_ws;
  float* agg    = (float*)(ws);                                   // ndst*128 f32
  size_t off    = (size_t)ndst * D * sizeof(float);
  float* w1T    = (float*)(ws + off);  off += (size_t)D * D * sizeof(float);
  float* w2T    = (float*)(ws + off);  off += (size_t)D * D * sizeof(float);
  int*   csr    = (int*)(ws + off);    off += (size_t)E * sizeof(int);
  int*   cnt    = (int*)(ws + off);    off += (size_t)ndst * sizeof(int);
  int*   offs   = (int*)(ws + off);    off += ((size_t)ndst + 1) * sizeof(int);
  int*   cursor = (int*)(ws + off);

  hipMemsetAsync(cnt, 0, (size_t)ndst * sizeof(int), stream);

  int eblocks = (E + 255) / 256;
  hist_kernel<<<eblocks, 256, 0, stream>>>(dst, cnt, E);
  scan_kernel<<<1, 1024, 0, stream>>>(cnt, offs, cursor, ndst);
  scatter_csr<<<eblocks, 256, 0, stream>>>(src, dst, cursor, csr, E);

  gather_rows<<<(ndst + 3) / 4, 256, 0, stream>>>(feat, csr, offs, agg, ndst);

  transpose_w<<<(D * D + 255) / 256, 256, 0, stream>>>(w1, w2, w1T, w2T);

  out_gemm<<<(ndst + MT - 1) / MT, 256, 0, stream>>>(
      feat, in_norm, agg, w1T, w2T, b1, b2, out, ndst);
}

// Round 3
// 148.793 us; speedup vs baseline: 9.8822x; 1.5484x over previous
//
#include <hip/hip_runtime.h>

#define D 128
#define KK 256  // concatenated K (feat | ah)

typedef __attribute__((ext_vector_type(8))) short short8;
typedef __attribute__((ext_vector_type(4))) float f32x4;

__device__ __forceinline__ ushort f2bf(float x) {  // RNE f32 -> bf16 bits
  union { float f; uint u; } v; v.f = x;
  uint r = v.u + 0x7fffu + ((v.u >> 16) & 1u);
  return (ushort)(r >> 16);
}
__device__ __forceinline__ float bf2f(uint b) {
  union { uint u; float f; } v; v.u = b << 16;
  return v.f;
}

// ---------------------------------------------------------------------------
// Scan of capacities derived from in_norm (= max(deg,1), exact ints).
// Single block, 1024 threads. Writes offs + cursor (cursor starts at offs).
// ---------------------------------------------------------------------------
__global__ __launch_bounds__(1024) void scan_kernel(
    const float* __restrict__ in_norm, int* __restrict__ offs,
    int* __restrict__ cursor, int n) {
  __shared__ int part[1024];
  int t = threadIdx.x;
  int ch = (n + 1023) >> 10;
  int beg = t * ch;
  int end = min(beg + ch, n);
  int s = 0;
  for (int i = beg; i < end; ++i) s += (int)in_norm[i];
  part[t] = s;
  __syncthreads();
  for (int off = 1; off < 1024; off <<= 1) {
    int v = part[t];
    int add = (t >= off) ? part[t - off] : 0;
    __syncthreads();
    part[t] = v + add;
    __syncthreads();
  }
  int base = (t == 0) ? 0 : part[t - 1];
  for (int i = beg; i < end; ++i) {
    offs[i] = base;
    cursor[i] = base;
    base += (int)in_norm[i];
  }
  if (t == 0) offs[n] = part[1023];
}

__global__ __launch_bounds__(256) void scatter_csr(
    const int* __restrict__ src, const int* __restrict__ dst,
    int* __restrict__ cursor, int* __restrict__ csr, int E) {
  int e = blockIdx.x * 256 + threadIdx.x;
  if (e < E) {
    int p = atomicAdd(&cursor[dst[e]], 1);
    csr[p] = src[e];
  }
}

// feat f32 -> bf16 (all N_SRC rows)
__global__ __launch_bounds__(256) void convert_feat(
    const float* __restrict__ feat, ushort* __restrict__ featb, int total4) {
  int i = blockIdx.x * 256 + threadIdx.x;
  if (i < total4) {
    float4 f = ((const float4*)feat)[i];
    ushort4 u;
    u.x = f2bf(f.x); u.y = f2bf(f.y); u.z = f2bf(f.z); u.w = f2bf(f.w);
    ((ushort4*)featb)[i] = u;
  }
}

// W[o][k] bf16, k<128 from w1, k>=128 from w2 (row stride KK=256)
__global__ __launch_bounds__(256) void convert_w(
    const float* __restrict__ w1, const float* __restrict__ w2,
    ushort* __restrict__ W) {
  int idx = blockIdx.x * 256 + threadIdx.x;
  if (idx < D * D) {
    int o = idx >> 7, k = idx & (D - 1);
    W[o * KK + k]     = f2bf(w1[idx]);
    W[o * KK + D + k] = f2bf(w2[idx]);
  }
}

// ---------------------------------------------------------------------------
// dst-major gather from bf16 feat; one wave per row, 4B (bf16x2) per lane,
// f32 accumulation, /in_norm folded in, ah stored f32 into d_out.
// ---------------------------------------------------------------------------
__global__ __launch_bounds__(256) void gather_rows(
    const ushort* __restrict__ featb, const int* __restrict__ csr,
    const int* __restrict__ offs, const int* __restrict__ cursor,
    const float* __restrict__ in_norm, float* __restrict__ ah, int ndst) {
  int row = blockIdx.x * 4 + (threadIdx.x >> 6);
  if (row >= ndst) return;
  int lane = threadIdx.x & 63;
  int beg = offs[row], end = cursor[row];
  float x0 = 0.f, y0 = 0.f, x1 = 0.f, y1 = 0.f;
  float x2 = 0.f, y2 = 0.f, x3 = 0.f, y3 = 0.f;
  int j = beg;
  for (; j + 3 < end; j += 4) {
    int u0 = csr[j], u1 = csr[j + 1], u2 = csr[j + 2], u3 = csr[j + 3];
    uint p0 = ((const uint*)(featb + (size_t)u0 * D))[lane];
    uint p1 = ((const uint*)(featb + (size_t)u1 * D))[lane];
    uint p2 = ((const uint*)(featb + (size_t)u2 * D))[lane];
    uint p3 = ((const uint*)(featb + (size_t)u3 * D))[lane];
    x0 += bf2f(p0 & 0xffffu); y0 += bf2f(p0 >> 16);
    x1 += bf2f(p1 & 0xffffu); y1 += bf2f(p1 >> 16);
    x2 += bf2f(p2 & 0xffffu); y2 += bf2f(p2 >> 16);
    x3 += bf2f(p3 & 0xffffu); y3 += bf2f(p3 >> 16);
  }
  for (; j < end; ++j) {
    uint p = ((const uint*)(featb + (size_t)csr[j] * D))[lane];
    x0 += bf2f(p & 0xffffu); y0 += bf2f(p >> 16);
  }
  float inv = 1.0f / in_norm[row];
  ((float2*)(ah + (size_t)row * D))[lane] =
      make_float2((x0 + x1 + x2 + x3) * inv, (y0 + y1 + y2 + y3) * inv);
}

// ---------------------------------------------------------------------------
// MFMA GEMM: out[m][o] = sum_k featb[m][k]*W[o][k] (k<128)
//                      + sum_k ah[m][k]*W[o][128+k] + b1[o]+b2[o]
// Block = 4 waves = 64 rows; wave = 16 rows x 128 cols; K=256 in 8 steps.
// A layout (16x16x32): lane holds A[lane&15][(lane>>4)*8 + i]
// B layout:            lane holds B[(lane>>4)*8 + i][lane&15] = W[n][k...]
// C/D layout:          col = lane&15, row = (lane>>4)*4 + reg
// ah is read from d_out and overwritten by the same wave only -> race-free.
// ---------------------------------------------------------------------------
__global__ __launch_bounds__(256) void gemm_mfma(
    const ushort* __restrict__ featb, const float* __restrict__ ah,
    const ushort* __restrict__ W, const float* __restrict__ b1,
    const float* __restrict__ b2, float* __restrict__ out, int ndst) {
  int wid = threadIdx.x >> 6;
  int lane = threadIdx.x & 63;
  int row0 = blockIdx.x * 64 + wid * 16;
  int r = lane & 15;
  int kg = lane >> 4;
  int arow = row0 + r;
  if (arow >= ndst) arow = ndst - 1;  // clamped lanes' results are discarded

  short8 afrag[8];
  const ushort* fr = featb + (size_t)arow * D;
#pragma unroll
  for (int s = 0; s < 4; ++s)
    afrag[s] = *(const short8*)(fr + s * 32 + kg * 8);
  const float* ar = ah + (size_t)arow * D;
#pragma unroll
  for (int s = 0; s < 4; ++s) {
    float4 lo = *(const float4*)(ar + s * 32 + kg * 8);
    float4 hi = *(const float4*)(ar + s * 32 + kg * 8 + 4);
    short8 t;
    t[0] = (short)f2bf(lo.x); t[1] = (short)f2bf(lo.y);
    t[2] = (short)f2bf(lo.z); t[3] = (short)f2bf(lo.w);
    t[4] = (short)f2bf(hi.x); t[5] = (short)f2bf(hi.y);
    t[6] = (short)f2bf(hi.z); t[7] = (short)f2bf(hi.w);
    afrag[4 + s] = t;
  }

  f32x4 acc[8];
#pragma unroll
  for (int n = 0; n < 8; ++n) acc[n] = (f32x4){0.f, 0.f, 0.f, 0.f};

#pragma unroll
  for (int n = 0; n < 8; ++n) {
    const ushort* wr = W + (size_t)(n * 16 + r) * KK;
#pragma unroll
    for (int s = 0; s < 8; ++s) {
      short8 bfrag = *(const short8*)(wr + s * 32 + kg * 8);
      acc[n] = __builtin_amdgcn_mfma_f32_16x16x32_bf16(afrag[s], bfrag, acc[n], 0, 0, 0);
    }
  }

#pragma unroll
  for (int n = 0; n < 8; ++n) {
    int col = n * 16 + r;
    float bb = b1[col] + b2[col];
#pragma unroll
    for (int q = 0; q < 4; ++q) {
      int orow = row0 + kg * 4 + q;
      if (orow < ndst) out[(size_t)orow * D + col] = acc[n][q] + bb;
    }
  }
}

extern "C" void kernel_launch(void* const* d_in, const int* in_sizes, int n_in,
                              void* d_out, int out_size, void* d_ws, size_t ws_size,
                              hipStream_t stream) {
  const float* feat    = (const float*)d_in[0];
  const float* in_norm = (const float*)d_in[1];
  const float* w1      = (const float*)d_in[2];
  const float* b1      = (const float*)d_in[3];
  const float* w2      = (const float*)d_in[4];
  const float* b2      = (const float*)d_in[5];
  const int*   src     = (const int*)d_in[6];
  const int*   dst     = (const int*)d_in[7];
  float*       out     = (float*)d_out;

  int E    = in_sizes[6];
  int ndst = in_sizes[1];
  int featn = in_sizes[0];  // N_SRC * D

  // workspace layout
  char* ws = (char*)d_ws;
  ushort* featb = (ushort*)ws;                               // featn bf16
  size_t off = (size_t)featn * sizeof(ushort);
  ushort* W = (ushort*)(ws + off);  off += (size_t)D * KK * sizeof(ushort);
  int* csr = (int*)(ws + off);      off += ((size_t)E + ndst) * sizeof(int);
  int* offs = (int*)(ws + off);     off += ((size_t)ndst + 1) * sizeof(int);
  int* cursor = (int*)(ws + off);

  scan_kernel<<<1, 1024, 0, stream>>>(in_norm, offs, cursor, ndst);
  scatter_csr<<<(E + 255) / 256, 256, 0, stream>>>(src, dst, cursor, csr, E);

  int total4 = featn / 4;
  convert_feat<<<(total4 + 255) / 256, 256, 0, stream>>>(feat, featb, total4);
  convert_w<<<(D * D + 255) / 256, 256, 0, stream>>>(w1, w2, W);

  gather_rows<<<(ndst + 3) / 4, 256, 0, stream>>>(
      featb, csr, offs, cursor, in_norm, out, ndst);

  gemm_mfma<<<(ndst + 63) / 64, 256, 0, stream>>>(
      featb, out, W, b1, b2, out, ndst);
}

// Round 4
// 113.198 us; speedup vs baseline: 12.9896x; 1.3144x over previous
//
#include <hip/hip_runtime.h>

#define D 128
#define KK 256  // concatenated K (feat | ah)

typedef __attribute__((ext_vector_type(8))) short short8;
typedef __attribute__((ext_vector_type(4))) float f32x4;

__device__ __forceinline__ ushort f2bf(float x) {  // RNE f32 -> bf16 bits
  union { float f; uint u; } v; v.f = x;
  uint r = v.u + 0x7fffu + ((v.u >> 16) & 1u);
  return (ushort)(r >> 16);
}
__device__ __forceinline__ float bf2f(uint b) {
  union { uint u; float f; } v; v.u = b << 16;
  return v.f;
}

// ---------------------------------------------------------------------------
// 3-phase multi-block exclusive scan of capacities (int)in_norm[i].
// in_norm = max(deg,1) exactly (integer-valued), so it doubles as the
// capacity table; cursor[v] after scatter gives the true segment end.
// ---------------------------------------------------------------------------
__global__ __launch_bounds__(256) void scan_p1(
    const float* __restrict__ in_norm, int* __restrict__ offs,
    int* __restrict__ bsums, int n) {
  __shared__ int tmp[256];
  int t = threadIdx.x;
  int i = blockIdx.x * 256 + t;
  int v = (i < n) ? (int)in_norm[i] : 0;
  tmp[t] = v;
  __syncthreads();
  for (int off = 1; off < 256; off <<= 1) {
    int a = tmp[t];
    int b = (t >= off) ? tmp[t - off] : 0;
    __syncthreads();
    tmp[t] = a + b;
    __syncthreads();
  }
  if (i < n) offs[i] = tmp[t] - v;  // exclusive intra-block
  if (t == 255) bsums[blockIdx.x] = tmp[255];
}

// single small block: exclusive scan of block sums in place (nb <= 256)
__global__ __launch_bounds__(256) void scan_p2(int* __restrict__ bsums, int nb) {
  __shared__ int tmp[256];
  int t = threadIdx.x;
  int v = (t < nb) ? bsums[t] : 0;
  tmp[t] = v;
  __syncthreads();
  for (int off = 1; off < 256; off <<= 1) {
    int a = tmp[t];
    int b = (t >= off) ? tmp[t - off] : 0;
    __syncthreads();
    tmp[t] = a + b;
    __syncthreads();
  }
  if (t < nb) bsums[t] = tmp[t] - v;
}

__global__ __launch_bounds__(256) void scan_p3(
    int* __restrict__ offs, const int* __restrict__ bsums,
    int* __restrict__ cursor, int n) {
  int i = blockIdx.x * 256 + threadIdx.x;
  if (i < n) {
    int o = offs[i] + bsums[blockIdx.x];
    offs[i] = o;
    cursor[i] = o;
  }
}

__global__ __launch_bounds__(256) void scatter_csr(
    const int* __restrict__ src, const int* __restrict__ dst,
    int* __restrict__ cursor, int* __restrict__ csr, int E) {
  int e = blockIdx.x * 256 + threadIdx.x;
  if (e < E) {
    int p = atomicAdd(&cursor[dst[e]], 1);
    csr[p] = src[e];
  }
}

// feat f32 -> bf16 (all N_SRC rows)
__global__ __launch_bounds__(256) void convert_feat(
    const float* __restrict__ feat, ushort* __restrict__ featb, int total4) {
  int i = blockIdx.x * 256 + threadIdx.x;
  if (i < total4) {
    float4 f = ((const float4*)feat)[i];
    ushort4 u;
    u.x = f2bf(f.x); u.y = f2bf(f.y); u.z = f2bf(f.z); u.w = f2bf(f.w);
    ((ushort4*)featb)[i] = u;
  }
}

// W[o][k] bf16, k<128 from w1, k>=128 from w2 (row stride KK=256)
__global__ __launch_bounds__(256) void convert_w(
    const float* __restrict__ w1, const float* __restrict__ w2,
    ushort* __restrict__ W) {
  int idx = blockIdx.x * 256 + threadIdx.x;
  if (idx < D * D) {
    int o = idx >> 7, k = idx & (D - 1);
    W[o * KK + k]     = f2bf(w1[idx]);
    W[o * KK + D + k] = f2bf(w2[idx]);
  }
}

// ---------------------------------------------------------------------------
// dst-major gather from bf16 feat; one wave per row, 4B (bf16x2) per lane,
// f32 accumulation, /in_norm folded in, ah stored f32 into d_out.
// ---------------------------------------------------------------------------
__global__ __launch_bounds__(256) void gather_rows(
    const ushort* __restrict__ featb, const int* __restrict__ csr,
    const int* __restrict__ offs, const int* __restrict__ cursor,
    const float* __restrict__ in_norm, float* __restrict__ ah, int ndst) {
  int row = blockIdx.x * 4 + (threadIdx.x >> 6);
  if (row >= ndst) return;
  int lane = threadIdx.x & 63;
  int beg = offs[row], end = cursor[row];
  float x0 = 0.f, y0 = 0.f, x1 = 0.f, y1 = 0.f;
  float x2 = 0.f, y2 = 0.f, x3 = 0.f, y3 = 0.f;
  int j = beg;
  for (; j + 3 < end; j += 4) {
    int u0 = csr[j], u1 = csr[j + 1], u2 = csr[j + 2], u3 = csr[j + 3];
    uint p0 = ((const uint*)(featb + (size_t)u0 * D))[lane];
    uint p1 = ((const uint*)(featb + (size_t)u1 * D))[lane];
    uint p2 = ((const uint*)(featb + (size_t)u2 * D))[lane];
    uint p3 = ((const uint*)(featb + (size_t)u3 * D))[lane];
    x0 += bf2f(p0 & 0xffffu); y0 += bf2f(p0 >> 16);
    x1 += bf2f(p1 & 0xffffu); y1 += bf2f(p1 >> 16);
    x2 += bf2f(p2 & 0xffffu); y2 += bf2f(p2 >> 16);
    x3 += bf2f(p3 & 0xffffu); y3 += bf2f(p3 >> 16);
  }
  for (; j < end; ++j) {
    uint p = ((const uint*)(featb + (size_t)csr[j] * D))[lane];
    x0 += bf2f(p & 0xffffu); y0 += bf2f(p >> 16);
  }
  float inv = 1.0f / in_norm[row];
  ((float2*)(ah + (size_t)row * D))[lane] =
      make_float2((x0 + x1 + x2 + x3) * inv, (y0 + y1 + y2 + y3) * inv);
}

// ---------------------------------------------------------------------------
// MFMA GEMM: out[m][o] = sum_k featb[m][k]*W[o][k] (k<128)
//                      + sum_k ah[m][k]*W[o][128+k] + b1[o]+b2[o]
// Block = 4 waves = 64 rows; wave = 16 rows x 128 cols; K=256 in 8 steps.
// ah is read from d_out and overwritten by the same wave only -> race-free.
// ---------------------------------------------------------------------------
__global__ __launch_bounds__(256) void gemm_mfma(
    const ushort* __restrict__ featb, const float* __restrict__ ah,
    const ushort* __restrict__ W, const float* __restrict__ b1,
    const float* __restrict__ b2, float* __restrict__ out, int ndst) {
  int wid = threadIdx.x >> 6;
  int lane = threadIdx.x & 63;
  int row0 = blockIdx.x * 64 + wid * 16;
  int r = lane & 15;
  int kg = lane >> 4;
  int arow = row0 + r;
  if (arow >= ndst) arow = ndst - 1;  // clamped lanes' results are discarded

  short8 afrag[8];
  const ushort* fr = featb + (size_t)arow * D;
#pragma unroll
  for (int s = 0; s < 4; ++s)
    afrag[s] = *(const short8*)(fr + s * 32 + kg * 8);
  const float* ar = ah + (size_t)arow * D;
#pragma unroll
  for (int s = 0; s < 4; ++s) {
    float4 lo = *(const float4*)(ar + s * 32 + kg * 8);
    float4 hi = *(const float4*)(ar + s * 32 + kg * 8 + 4);
    short8 t;
    t[0] = (short)f2bf(lo.x); t[1] = (short)f2bf(lo.y);
    t[2] = (short)f2bf(lo.z); t[3] = (short)f2bf(lo.w);
    t[4] = (short)f2bf(hi.x); t[5] = (short)f2bf(hi.y);
    t[6] = (short)f2bf(hi.z); t[7] = (short)f2bf(hi.w);
    afrag[4 + s] = t;
  }

  f32x4 acc[8];
#pragma unroll
  for (int n = 0; n < 8; ++n) acc[n] = (f32x4){0.f, 0.f, 0.f, 0.f};

#pragma unroll
  for (int n = 0; n < 8; ++n) {
    const ushort* wr = W + (size_t)(n * 16 + r) * KK;
#pragma unroll
    for (int s = 0; s < 8; ++s) {
      short8 bfrag = *(const short8*)(wr + s * 32 + kg * 8);
      acc[n] = __builtin_amdgcn_mfma_f32_16x16x32_bf16(afrag[s], bfrag, acc[n], 0, 0, 0);
    }
  }

#pragma unroll
  for (int n = 0; n < 8; ++n) {
    int col = n * 16 + r;
    float bb = b1[col] + b2[col];
#pragma unroll
    for (int q = 0; q < 4; ++q) {
      int orow = row0 + kg * 4 + q;
      if (orow < ndst) out[(size_t)orow * D + col] = acc[n][q] + bb;
    }
  }
}

extern "C" void kernel_launch(void* const* d_in, const int* in_sizes, int n_in,
                              void* d_out, int out_size, void* d_ws, size_t ws_size,
                              hipStream_t stream) {
  const float* feat    = (const float*)d_in[0];
  const float* in_norm = (const float*)d_in[1];
  const float* w1      = (const float*)d_in[2];
  const float* b1      = (const float*)d_in[3];
  const float* w2      = (const float*)d_in[4];
  const float* b2      = (const float*)d_in[5];
  const int*   src     = (const int*)d_in[6];
  const int*   dst     = (const int*)d_in[7];
  float*       out     = (float*)d_out;

  int E    = in_sizes[6];
  int ndst = in_sizes[1];
  int featn = in_sizes[0];  // N_SRC * D

  // workspace layout
  char* ws = (char*)d_ws;
  ushort* featb = (ushort*)ws;                               // featn bf16
  size_t off = (size_t)featn * sizeof(ushort);
  ushort* W = (ushort*)(ws + off);  off += (size_t)D * KK * sizeof(ushort);
  int* csr = (int*)(ws + off);      off += ((size_t)E + ndst) * sizeof(int);
  int* offs = (int*)(ws + off);     off += ((size_t)ndst + 1) * sizeof(int);
  int* cursor = (int*)(ws + off);   off += (size_t)ndst * sizeof(int);
  int* bsums = (int*)(ws + off);

  int nb = (ndst + 255) / 256;  // 98 <= 256
  scan_p1<<<nb, 256, 0, stream>>>(in_norm, offs, bsums, ndst);
  scan_p2<<<1, 256, 0, stream>>>(bsums, nb);
  scan_p3<<<nb, 256, 0, stream>>>(offs, bsums, cursor, ndst);

  scatter_csr<<<(E + 255) / 256, 256, 0, stream>>>(src, dst, cursor, csr, E);

  int total4 = featn / 4;
  convert_feat<<<(total4 + 255) / 256, 256, 0, stream>>>(feat, featb, total4);
  convert_w<<<(D * D + 255) / 256, 256, 0, stream>>>(w1, w2, W);

  gather_rows<<<(ndst + 3) / 4, 256, 0, stream>>>(
      featb, csr, offs, cursor, in_norm, out, ndst);

  gemm_mfma<<<(ndst + 63) / 64, 256, 0, stream>>>(
      featb, out, W, b1, b2, out, ndst);
}

// Round 5
// 104.907 us; speedup vs baseline: 14.0162x; 1.0790x over previous
//
#include <hip/hip_runtime.h>

#define D 128
#define KK 256  // concatenated K (feat | ah)

typedef __attribute__((ext_vector_type(8))) short short8;
typedef __attribute__((ext_vector_type(4))) float f32x4;

__device__ __forceinline__ ushort f2bf(float x) {  // RNE f32 -> bf16 bits
  union { float f; uint u; } v; v.f = x;
  uint r = v.u + 0x7fffu + ((v.u >> 16) & 1u);
  return (ushort)(r >> 16);
}
__device__ __forceinline__ float bf2f(uint b) {
  union { uint u; float f; } v; v.u = b << 16;
  return v.f;
}

// ---------------------------------------------------------------------------
// Fused: feat f32 -> bf16 convert (all blocks, 4 float4/thread)
//      + scan phase 1 (blocks < nb: intra-block excl scan of (int)in_norm)
// ---------------------------------------------------------------------------
__global__ __launch_bounds__(256) void conv_scan(
    const float* __restrict__ feat, ushort* __restrict__ featb, int total4,
    const float* __restrict__ in_norm, int* __restrict__ offs,
    int* __restrict__ bsums, int n) {
  int tid = blockIdx.x * 256 + threadIdx.x;
#pragma unroll
  for (int t = 0; t < 4; ++t) {
    int i = tid * 4 + t;
    if (i < total4) {
      float4 f = ((const float4*)feat)[i];
      ushort4 u;
      u.x = f2bf(f.x); u.y = f2bf(f.y); u.z = f2bf(f.z); u.w = f2bf(f.w);
      ((ushort4*)featb)[i] = u;
    }
  }
  int nb = (n + 255) >> 8;
  if ((int)blockIdx.x < nb) {
    __shared__ int tmp[256];
    int t = threadIdx.x;
    int i = blockIdx.x * 256 + t;
    int v = (i < n) ? (int)in_norm[i] : 0;
    tmp[t] = v;
    __syncthreads();
    for (int off = 1; off < 256; off <<= 1) {
      int a = tmp[t];
      int b = (t >= off) ? tmp[t - off] : 0;
      __syncthreads();
      tmp[t] = a + b;
      __syncthreads();
    }
    if (i < n) offs[i] = tmp[t] - v;  // exclusive intra-block
    if (t == 255) bsums[blockIdx.x] = tmp[255];
  }
}

// ---------------------------------------------------------------------------
// Fused: scan phase 2 (block 0: excl scan of bsums, nb<=256)
//      + W convert (blocks 1..64): W[o][k]=w1, W[o][128+k]=w2, bf16
// ---------------------------------------------------------------------------
__global__ __launch_bounds__(256) void p2_convw(
    int* __restrict__ bsums, int nb, const float* __restrict__ w1,
    const float* __restrict__ w2, ushort* __restrict__ W) {
  if (blockIdx.x == 0) {
    __shared__ int tmp[256];
    int t = threadIdx.x;
    int v = (t < nb) ? bsums[t] : 0;
    tmp[t] = v;
    __syncthreads();
    for (int off = 1; off < 256; off <<= 1) {
      int a = tmp[t];
      int b = (t >= off) ? tmp[t - off] : 0;
      __syncthreads();
      tmp[t] = a + b;
      __syncthreads();
    }
    if (t < nb) bsums[t] = tmp[t] - v;
  } else {
    int idx = (blockIdx.x - 1) * 256 + threadIdx.x;  // 0..16383
    if (idx < D * D) {
      int o = idx >> 7, k = idx & (D - 1);
      W[o * KK + k]     = f2bf(w1[idx]);
      W[o * KK + D + k] = f2bf(w2[idx]);
    }
  }
}

__global__ __launch_bounds__(256) void scan_p3(
    int* __restrict__ offs, const int* __restrict__ bsums,
    int* __restrict__ cursor, int n) {
  int i = blockIdx.x * 256 + threadIdx.x;
  if (i < n) {
    int o = offs[i] + bsums[blockIdx.x];
    offs[i] = o;
    cursor[i] = o;
  }
}

__global__ __launch_bounds__(256) void scatter_csr(
    const int* __restrict__ src, const int* __restrict__ dst,
    int* __restrict__ cursor, ushort* __restrict__ csr, int E) {
  int e = blockIdx.x * 256 + threadIdx.x;
  if (e < E) {
    int p = atomicAdd(&cursor[dst[e]], 1);
    csr[p] = (ushort)src[e];
  }
}

// ---------------------------------------------------------------------------
// dst-major gather from bf16 feat; one wave per row, 4B (bf16x2) per lane,
// 8-deep ILP, f32 accumulation, /in_norm folded in, ah written as bf16.
// ---------------------------------------------------------------------------
__global__ __launch_bounds__(256) void gather_rows(
    const ushort* __restrict__ featb, const ushort* __restrict__ csr,
    const int* __restrict__ offs, const int* __restrict__ cursor,
    const float* __restrict__ in_norm, ushort* __restrict__ ahb, int ndst) {
  int row = blockIdx.x * 4 + (threadIdx.x >> 6);
  if (row >= ndst) return;
  int lane = threadIdx.x & 63;
  int beg = offs[row], end = cursor[row];
  float x[8], y[8];
#pragma unroll
  for (int t = 0; t < 8; ++t) { x[t] = 0.f; y[t] = 0.f; }
  int j = beg;
  for (; j + 7 < end; j += 8) {
    uint p[8];
#pragma unroll
    for (int t = 0; t < 8; ++t) {
      int u = csr[j + t];
      p[t] = ((const uint*)(featb + (size_t)u * D))[lane];
    }
#pragma unroll
    for (int t = 0; t < 8; ++t) {
      x[t] += bf2f(p[t] & 0xffffu);
      y[t] += bf2f(p[t] >> 16);
    }
  }
  int t = 0;
  for (; j < end; ++j, ++t) {
    uint p = ((const uint*)(featb + (size_t)csr[j] * D))[lane];
    x[t & 7] += bf2f(p & 0xffffu);
    y[t & 7] += bf2f(p >> 16);
  }
  float xs = ((x[0] + x[1]) + (x[2] + x[3])) + ((x[4] + x[5]) + (x[6] + x[7]));
  float ys = ((y[0] + y[1]) + (y[2] + y[3])) + ((y[4] + y[5]) + (y[6] + y[7]));
  float inv = 1.0f / in_norm[row];
  uint packed = ((uint)f2bf(ys * inv) << 16) | (uint)f2bf(xs * inv);
  ((uint*)(ahb + (size_t)row * D))[lane] = packed;
}

// ---------------------------------------------------------------------------
// MFMA GEMM: out[m][o] = sum_k featb[m][k]*W[o][k] (k<128)
//                      + sum_k ahb[m][k]*W[o][128+k] + b1[o]+b2[o]
// Block = 4 waves = 64 rows; wave = 16 rows x 128 cols; K=256 in 8 steps.
// ---------------------------------------------------------------------------
__global__ __launch_bounds__(256) void gemm_mfma(
    const ushort* __restrict__ featb, const ushort* __restrict__ ahb,
    const ushort* __restrict__ W, const float* __restrict__ b1,
    const float* __restrict__ b2, float* __restrict__ out, int ndst) {
  int wid = threadIdx.x >> 6;
  int lane = threadIdx.x & 63;
  int row0 = blockIdx.x * 64 + wid * 16;
  int r = lane & 15;
  int kg = lane >> 4;
  int arow = row0 + r;
  if (arow >= ndst) arow = ndst - 1;  // clamped lanes' results are discarded

  short8 afrag[8];
  const ushort* fr = featb + (size_t)arow * D;
  const ushort* ar = ahb + (size_t)arow * D;
#pragma unroll
  for (int s = 0; s < 4; ++s) {
    afrag[s]     = *(const short8*)(fr + s * 32 + kg * 8);
    afrag[4 + s] = *(const short8*)(ar + s * 32 + kg * 8);
  }

  f32x4 acc[8];
#pragma unroll
  for (int n = 0; n < 8; ++n) acc[n] = (f32x4){0.f, 0.f, 0.f, 0.f};

#pragma unroll
  for (int n = 0; n < 8; ++n) {
    const ushort* wr = W + (size_t)(n * 16 + r) * KK;
#pragma unroll
    for (int s = 0; s < 8; ++s) {
      short8 bfrag = *(const short8*)(wr + s * 32 + kg * 8);
      acc[n] = __builtin_amdgcn_mfma_f32_16x16x32_bf16(afrag[s], bfrag, acc[n], 0, 0, 0);
    }
  }

#pragma unroll
  for (int n = 0; n < 8; ++n) {
    int col = n * 16 + r;
    float bb = b1[col] + b2[col];
#pragma unroll
    for (int q = 0; q < 4; ++q) {
      int orow = row0 + kg * 4 + q;
      if (orow < ndst) out[(size_t)orow * D + col] = acc[n][q] + bb;
    }
  }
}

extern "C" void kernel_launch(void* const* d_in, const int* in_sizes, int n_in,
                              void* d_out, int out_size, void* d_ws, size_t ws_size,
                              hipStream_t stream) {
  const float* feat    = (const float*)d_in[0];
  const float* in_norm = (const float*)d_in[1];
  const float* w1      = (const float*)d_in[2];
  const float* b1      = (const float*)d_in[3];
  const float* w2      = (const float*)d_in[4];
  const float* b2      = (const float*)d_in[5];
  const int*   src     = (const int*)d_in[6];
  const int*   dst     = (const int*)d_in[7];
  float*       out     = (float*)d_out;

  int E    = in_sizes[6];
  int ndst = in_sizes[1];
  int featn = in_sizes[0];  // N_SRC * D

  // workspace layout
  char* ws = (char*)d_ws;
  ushort* featb = (ushort*)ws;                                // featn bf16
  size_t off = (size_t)featn * sizeof(ushort);
  ushort* ahb = (ushort*)(ws + off);  off += (size_t)ndst * D * sizeof(ushort);
  ushort* W = (ushort*)(ws + off);    off += (size_t)D * KK * sizeof(ushort);
  ushort* csr = (ushort*)(ws + off);  off += (((size_t)E + ndst + 1) & ~1ull) * sizeof(ushort);
  int* offs = (int*)(ws + off);       off += (size_t)ndst * sizeof(int);
  int* cursor = (int*)(ws + off);     off += (size_t)ndst * sizeof(int);
  int* bsums = (int*)(ws + off);

  int total4 = featn / 4;                      // # float4 in feat
  int cblocks = (total4 / 4 + 255) / 256;      // 4 float4 per thread
  int nb = (ndst + 255) / 256;                 // scan blocks (98 <= 256)
  if (cblocks < nb) cblocks = nb;

  conv_scan<<<cblocks, 256, 0, stream>>>(feat, featb, total4, in_norm, offs, bsums, ndst);
  p2_convw<<<1 + (D * D + 255) / 256, 256, 0, stream>>>(bsums, nb, w1, w2, W);
  scan_p3<<<nb, 256, 0, stream>>>(offs, bsums, cursor, ndst);
  scatter_csr<<<(E + 255) / 256, 256, 0, stream>>>(src, dst, cursor, csr, E);
  gather_rows<<<(ndst + 3) / 4, 256, 0, stream>>>(
      featb, csr, offs, cursor, in_norm, ahb, ndst);
  gemm_mfma<<<(ndst + 63) / 64, 256, 0, stream>>>(
      featb, ahb, W, b1, b2, out, ndst);
}